// Round 10
// baseline (6406.083 us; speedup 1.0000x reference)
//
#include <hip/hip_runtime.h>
#include <math.h>

#define S_LEN 2048
#define HD 512
#define E_DIM 512
#define NTAG 12
#define TAG_START 10
#define TAG_STOP 11
#define NEGV -10000.0f

#define NCHUNK 256
#define CLEN 8            // steps per chunk (NCHUNK*CLEN == S_LEN)

// byte-repeating sentinel (memset 0x7F) = fp32 3.39e38; |h| < 1 can never equal it
#define SENT 0x7F7F7F7Fu

// ---------------- recurrence: r9 winner, ONE barrier per step ----------------
// 64 blocks/dir x 256 thr; Whh + Wih rows pinned in VGPRs; emb row double-buffered in LDS.
// Sync = r1's proven direct data-poll (relaxed agent atomics, unbounded).
// Barrier discipline: staging(s) -> BARRIER -> elds-write(s+1) -> dot(s) -> store(s).
// All waves passed BARRIER(s) => all completed staging(s) => all completed dot(s-1);
// every write between BARRIER(s) and BARRIER(s+1) targets buffers no lagging wave reads.
__global__ __attribute__((amdgpu_flat_work_group_size(256, 256), amdgpu_waves_per_eu(1, 1)))
void lstm_rec(
    const float* __restrict__ WhhF, const float* __restrict__ WhhB,
    const float* __restrict__ WihF, const float* __restrict__ WihB,
    const float* __restrict__ bihF, const float* __restrict__ bhhF,
    const float* __restrict__ bihB, const float* __restrict__ bhhB,
    const int* __restrict__ sent, const float* __restrict__ embed,
    const float* __restrict__ h0, const float* __restrict__ c0,
    unsigned* __restrict__ hfp, unsigned* __restrict__ hbp)
{
    const int bid = blockIdx.x;
    const int dir = bid >> 6;          // 0 fwd, 1 bwd
    const int b   = bid & 63;
    const float* __restrict__ Whh = dir ? WhhB : WhhF;
    const float* __restrict__ Wih = dir ? WihB : WihF;
    const float* __restrict__ bih = dir ? bihB : bihF;
    const float* __restrict__ bhh = dir ? bhhB : bhhF;
    unsigned* __restrict__ Hu = dir ? hbp : hfp;

    const int tid = threadIdx.x;
    const int r = tid >> 3;            // 0..31 local gate-row
    const int k = tid & 7;             // column chunk
    const int ul = r >> 2;             // 0..7 local unit
    const int g = r & 3;               // gate (i,f,g,o)
    const int unit = b * 8 + ul;
    const int row_g = g * HD + unit;   // global gate row in [0,2048)

    // 64 Whh + 64 Wih weights per thread as 32 NAMED float4s, pinned opaque (r3 mechanism)
    const float4* wp = (const float4*)(Whh + (size_t)row_g * HD + k * 64);
    const float4* up = (const float4*)(Wih + (size_t)row_g * E_DIM + k * 64);
#define WDECL(i) float4 w##i = wp[i]; float4 u##i = up[i];
    WDECL(0)  WDECL(1)  WDECL(2)  WDECL(3)
    WDECL(4)  WDECL(5)  WDECL(6)  WDECL(7)
    WDECL(8)  WDECL(9)  WDECL(10) WDECL(11)
    WDECL(12) WDECL(13) WDECL(14) WDECL(15)
#define WPIN(i) asm volatile("" : "+v"(w##i.x), "+v"(w##i.y), "+v"(w##i.z), "+v"(w##i.w), \
                                  "+v"(u##i.x), "+v"(u##i.y), "+v"(u##i.z), "+v"(u##i.w));
    WPIN(0)  WPIN(1)  WPIN(2)  WPIN(3)
    WPIN(4)  WPIN(5)  WPIN(6)  WPIN(7)
    WPIN(8)  WPIN(9)  WPIN(10) WPIN(11)
    WPIN(12) WPIN(13) WPIN(14) WPIN(15)

    __shared__ float hlds[2][8 * 68];  // double-buffered h row, stride 68 (conflict-free)
    __shared__ float elds[2][8 * 68];  // double-buffered emb row, same layout

    const int l  = tid & 63;
    const int l0 = l & 32;
    const bool cellln = (l & 31) == 0;
    float c = cellln ? c0[dir*HD + unit] : 0.f;

    // bias: constant across steps, added at k==0 lanes
    float xval = 0.f;
    if (k == 0) xval = bih[row_g] + bhh[row_g];

    const int ch  = tid >> 5;          // LDS staging slot
    const int off = (tid * 2) & 63;

    // ---- emb prologue: elds[0] <- row t(0); ereg <- row t(1) ----
    float2 ereg;
    {
        const int t0 = dir ? (S_LEN-1) : 0;
        const float2 ev = ((const float2*)(embed + (size_t)sent[t0] * E_DIM))[tid];
        elds[0][ch*68 + off]   = ev.x;
        elds[0][ch*68 + off+1] = ev.y;
        const int t1 = dir ? (S_LEN-2) : 1;
        ereg = ((const float2*)(embed + (size_t)sent[t1] * E_DIM))[tid];
    }

    for (int s = 0; s < S_LEN; ++s) {
        const int t_io = dir ? (S_LEN-1-s) : s;
        float* __restrict__ hl = hlds[s & 1];

        if (s == 0) {
            float2 hv = *(const float2*)(h0 + dir*HD + tid*2);
            hl[ch*68 + off]   = hv.x;
            hl[ch*68 + off+1] = hv.y;
        } else {
            const int prev = dir ? (t_io+1) : (t_io-1);
            const unsigned long long* src =
                (const unsigned long long*)(Hu + (size_t)prev*HD) + tid;
            unsigned long long v;
            do {
                v = __hip_atomic_load(src, __ATOMIC_RELAXED, __HIP_MEMORY_SCOPE_AGENT);
            } while ((unsigned)v == SENT || (unsigned)(v >> 32) == SENT);
            hl[ch*68 + off]   = __uint_as_float((unsigned)v);
            hl[ch*68 + off+1] = __uint_as_float((unsigned)(v >> 32));
        }
        __syncthreads();   // the ONLY barrier per step

        // write emb row for step s+1 (safe post-barrier: lagging waves read elds[s&1] only)
        {
            float* __restrict__ el = elds[(s+1) & 1];
            el[ch*68 + off]   = ereg.x;
            el[ch*68 + off+1] = ereg.y;
        }
        // prefetch emb row for step s+2
        if (s + 2 < S_LEN) {
            const int t2 = dir ? (t_io - 2) : (t_io + 2);
            ereg = ((const float2*)(embed + (size_t)sent[t2] * E_DIM))[tid];
        }

        // 64-wide dot chunk over h (Whh) AND emb (Wih); LDS reads are 8-lane broadcasts
        float a0 = 0.f, a1 = 0.f, a2 = 0.f, a3 = 0.f;
        const float* __restrict__ hp = &hl[k * 68];
        const float* __restrict__ ep = &elds[s & 1][k * 68];
#define WDOT(i) { const float4 hv = *(const float4*)(hp + 4*(i)); \
        a0 += w##i.x*hv.x; a1 += w##i.y*hv.y; a2 += w##i.z*hv.z; a3 += w##i.w*hv.w; } \
        { const float4 ev4 = *(const float4*)(ep + 4*(i)); \
        a0 += u##i.x*ev4.x; a1 += u##i.y*ev4.y; a2 += u##i.z*ev4.z; a3 += u##i.w*ev4.w; }
        WDOT(0)  WDOT(1)  WDOT(2)  WDOT(3)
        WDOT(4)  WDOT(5)  WDOT(6)  WDOT(7)
        WDOT(8)  WDOT(9)  WDOT(10) WDOT(11)
        WDOT(12) WDOT(13) WDOT(14) WDOT(15)
        float acc = (a0 + a1) + (a2 + a3);

        acc += __shfl_xor(acc, 1);
        acc += __shfl_xor(acc, 2);
        acc += __shfl_xor(acc, 4);
        const float pre = acc + xval;          // valid at k==0 lanes

        const float yy  = (g == 2) ? 2.f*pre : pre;
        const float sg  = 1.f / (1.f + __expf(-yy));
        const float act = (g == 2) ? 2.f*sg - 1.f : sg;

        const float a_i = __shfl(act, l0 + 0);
        const float a_f = __shfl(act, l0 + 8);
        const float a_g = __shfl(act, l0 + 16);
        const float a_o = __shfl(act, l0 + 24);

        float hval = 0.f;
        if (cellln) {
            c = a_f*c + a_i*a_g;
            const float th = 2.f / (1.f + __expf(-2.f*c)) - 1.f;
            hval = a_o * th;
        }
        const float h_hi = __shfl(hval, l0 ? 96 : 32, 64);
        if (l == 0) {
            const unsigned long long pv =
                (unsigned long long)__float_as_uint(hval) |
                ((unsigned long long)__float_as_uint(h_hi) << 32);
            unsigned long long* dst =
                (unsigned long long*)(Hu + (size_t)t_io*HD) + (unit >> 1);
            __hip_atomic_store(dst, pv, __ATOMIC_RELAXED, __HIP_MEMORY_SCOPE_AGENT);
        }
    }
}

// ---------------- feats: [hf,hb] @ Wout.T + bout ----------------
__global__ __launch_bounds__(256) void feats_k(
    const float* __restrict__ hf, const float* __restrict__ hb,
    const float* __restrict__ Wout, const float* __restrict__ bout,
    float* __restrict__ feats)
{
    int idx = blockIdx.x * blockDim.x + threadIdx.x;
    if (idx >= S_LEN * NTAG) return;
    int t = idx / NTAG, tag = idx - t*NTAG;
    const float* __restrict__ wf  = Wout + (size_t)tag * (2*HD);
    const float* __restrict__ ha  = hf + (size_t)t * HD;
    const float* __restrict__ hbr = hb + (size_t)t * HD;
    float a0=0.f, a1=0.f, a2=0.f, a3=0.f;
    for (int i = 0; i < HD; i += 4) {
        float4 h4 = *(const float4*)(ha + i);
        float4 w4 = *(const float4*)(wf + i);
        a0 += h4.x*w4.x; a1 += h4.y*w4.y; a2 += h4.z*w4.z; a3 += h4.w*w4.w;
    }
    for (int i = 0; i < HD; i += 4) {
        float4 h4 = *(const float4*)(hbr + i);
        float4 w4 = *(const float4*)(wf + HD + i);
        a0 += h4.x*w4.x; a1 += h4.y*w4.y; a2 += h4.z*w4.z; a3 += h4.w*w4.w;
    }
    feats[idx] = a0+a1+a2+a3 + bout[tag];
}

// ---------------- Viterbi pass A: per-chunk max-plus matrix composition ----------------
// C_chunk = M_{t7} (x) ... (x) M_{t0}, M_t[i][j] = trans[i][j] + feat[t][i].
// One wave per chunk; lane j holds column j of C.
__global__ __launch_bounds__(64) void vit_chunk(
    const float* __restrict__ feats, const float* __restrict__ trans,
    float* __restrict__ Cws)          // [NCHUNK][12][12]
{
    const int chunk = blockIdx.x;
    const int j = threadIdx.x;
    __shared__ float tr[NTAG*NTAG];
    for (int i = threadIdx.x; i < NTAG*NTAG; i += 64) tr[i] = trans[i];
    __syncthreads();
    if (j >= NTAG) return;

    const int t0 = chunk * CLEN;
    float c[NTAG];
    {
        const float* f0 = feats + (size_t)t0 * NTAG;
        #pragma unroll
        for (int i = 0; i < NTAG; ++i) c[i] = tr[i*NTAG + j] + f0[i];
    }
    for (int t = 1; t < CLEN; ++t) {
        const float* ft = feats + (size_t)(t0 + t) * NTAG;
        float cn[NTAG];
        #pragma unroll
        for (int i = 0; i < NTAG; ++i) {
            float m = tr[i*NTAG + 0] + c[0];
            #pragma unroll
            for (int k = 1; k < NTAG; ++k) m = fmaxf(m, tr[i*NTAG + k] + c[k]);
            cn[i] = m + ft[i];
        }
        #pragma unroll
        for (int i = 0; i < NTAG; ++i) c[i] = cn[i];
    }
    #pragma unroll
    for (int i = 0; i < NTAG; ++i) Cws[(size_t)chunk*NTAG*NTAG + i*NTAG + j] = c[i];
}

// ---------------- Viterbi pass B: serial scan over 256 chunk matrices ----------------
// fv replicated in every lane's registers; per chunk: lane i computes row-i max, 12 shfl rebroadcast.
__global__ __launch_bounds__(64) void vit_scan(
    const float* __restrict__ Cws, float* __restrict__ fvs)   // fvs: [NCHUNK+1][16]
{
    const int i = threadIdx.x;
    float fv[NTAG];
    #pragma unroll
    for (int p = 0; p < NTAG; ++p) fv[p] = (p == TAG_START) ? 0.f : NEGV;

    for (int c = 0; c < NCHUNK; ++c) {
        if (i < NTAG) fvs[c*16 + i] = fv[i];
        float m = -3.4e38f;
        if (i < NTAG) {
            const float* row = Cws + (size_t)c*NTAG*NTAG + i*NTAG;
            #pragma unroll
            for (int j = 0; j < NTAG; ++j) m = fmaxf(m, row[j] + fv[j]);
        }
        #pragma unroll
        for (int p = 0; p < NTAG; ++p) fv[p] = __shfl(m, p);
    }
    if (i < NTAG) fvs[NCHUNK*16 + i] = fv[i];
}

// ---------------- Viterbi pass C: parallel backpointer replay (reference semantics) ----------------
__global__ __launch_bounds__(64) void vit_bp(
    const float* __restrict__ feats, const float* __restrict__ trans,
    const float* __restrict__ fvs, unsigned char* __restrict__ bp)   // bp: [S_LEN][16]
{
    const int chunk = blockIdx.x;
    const int ln = threadIdx.x;
    float tr[NTAG];
    float fv = 0.f;
    if (ln < NTAG) {
        #pragma unroll
        for (int p = 0; p < NTAG; ++p) tr[p] = trans[ln*NTAG + p];
        fv = fvs[chunk*16 + ln];
    }
    const int t0 = chunk * CLEN;
    for (int t = 0; t < CLEN; ++t) {
        float sc[NTAG];
        #pragma unroll
        for (int p = 0; p < NTAG; ++p) sc[p] = __shfl(fv, p) + tr[p];
        float best = sc[0]; int arg = 0;
        #pragma unroll
        for (int p = 1; p < NTAG; ++p)
            if (sc[p] > best) { best = sc[p]; arg = p; }   // strict > = first-max (np argmax)
        if (ln < NTAG) {
            bp[(size_t)(t0 + t)*16 + ln] = (unsigned char)arg;
            fv = best + feats[(size_t)(t0 + t)*NTAG + ln];
        }
    }
}

// ---------------- Viterbi pass D: terminal + backtrace ----------------
__global__ __launch_bounds__(256) void vit_bt(
    const unsigned char* __restrict__ bp, const float* __restrict__ fvs,
    const float* __restrict__ trans, float* __restrict__ out)
{
    __shared__ unsigned char bpl[S_LEN * 16];   // 32 KB
    {
        const float4* src = (const float4*)bp;
        float4* dst = (float4*)bpl;
        for (int i = threadIdx.x; i < S_LEN*16/16; i += 256) dst[i] = src[i];
    }
    __syncthreads();
    if (threadIdx.x == 0) {
        float best = -3.4e38f; int arg = 0;
        #pragma unroll
        for (int i = 0; i < NTAG; ++i) {
            const float v = fvs[NCHUNK*16 + i] + trans[TAG_STOP*NTAG + i];
            if (v > best) { best = v; arg = i; }
        }
        out[0] = best;
        int tag = arg;
        for (int t = S_LEN-1; t >= 0; --t) {
            out[1+t] = (float)tag;
            tag = bpl[t*16 + tag];
        }
    }
}

// ---------------- launch ----------------
extern "C" void kernel_launch(void* const* d_in, const int* in_sizes, int n_in,
                              void* d_out, int out_size, void* d_ws, size_t ws_size,
                              hipStream_t stream)
{
    const int*   sent  = (const int*)d_in[0];
    const float* embed = (const float*)d_in[1];
    const float* WihF  = (const float*)d_in[2];
    const float* WhhF  = (const float*)d_in[3];
    const float* bihF  = (const float*)d_in[4];
    const float* bhhF  = (const float*)d_in[5];
    const float* WihB  = (const float*)d_in[6];
    const float* WhhB  = (const float*)d_in[7];
    const float* bihB  = (const float*)d_in[8];
    const float* bhhB  = (const float*)d_in[9];
    const float* h0    = (const float*)d_in[10];
    const float* c0    = (const float*)d_in[11];
    const float* Wout  = (const float*)d_in[12];
    const float* bout  = (const float*)d_in[13];
    const float* trans = (const float*)d_in[14];
    float* out = (float*)d_out;

    float* ws = (float*)d_ws;
    float* hf    = ws;                                       // 4 MB
    float* hb    = hf + (size_t)S_LEN * HD;                  // 4 MB
    float* feats = hb + (size_t)S_LEN * HD;                  // 96 KB
    float* Cws   = feats + (size_t)S_LEN * NTAG;             // 576 KB
    float* fvs   = Cws + (size_t)NCHUNK * NTAG * NTAG;       // 16.4 KB
    unsigned char* bp = (unsigned char*)(fvs + (size_t)(NCHUNK+1) * 16);  // 32 KB

    // 1) sentinel-fill both h buffers (byte pattern 0x7F -> fp32 3.39e38)
    hipMemsetAsync(hf, 0x7F, (size_t)2 * S_LEN * HD * sizeof(float), stream);
    // 2) recurrence with fused X computation, both directions concurrently
    lstm_rec<<<128, 256, 0, stream>>>(WhhF, WhhB, WihF, WihB,
                                      bihF, bhhF, bihB, bhhB,
                                      sent, embed, h0, c0,
                                      (unsigned*)hf, (unsigned*)hb);
    // 3) emission features
    {
        int n = S_LEN * NTAG;
        feats_k<<<(n + 255)/256, 256, 0, stream>>>(hf, hb, Wout, bout, feats);
    }
    // 4) Viterbi: parallel tropical scan (A,B,C) + backtrace (D)
    vit_chunk<<<NCHUNK, 64, 0, stream>>>(feats, trans, Cws);
    vit_scan<<<1, 64, 0, stream>>>(Cws, fvs);
    vit_bp<<<NCHUNK, 64, 0, stream>>>(feats, trans, fvs, bp);
    vit_bt<<<1, 256, 0, stream>>>(bp, fvs, trans, out);
}

// Round 11
// 4353.020 us; speedup vs baseline: 1.4716x; 1.4716x over previous
//
#include <hip/hip_runtime.h>
#include <math.h>

#define S_LEN 2048
#define HD 512
#define E_DIM 512
#define NTAG 12
#define TAG_START 10
#define TAG_STOP 11
#define NEGV -10000.0f

#define NCHUNK 256
#define CLEN 8            // steps per chunk (NCHUNK*CLEN == S_LEN)

// byte-repeating sentinel (memset 0x7F) = fp32 3.39e38; |h| < 1 can never equal it
#define SENT 0x7F7F7F7Fu

// ---------------- recurrence: r9 winner VERBATIM (two barriers per step) ----------------
// 64 blocks/dir x 256 thr; Whh + Wih rows pinned in VGPRs; emb row double-buffered in LDS.
// Sync = r1's proven direct data-poll (relaxed agent atomics, unbounded). The trailing
// barrier is part of the protocol: it throttles poll pressure so producer stores stay fast
// (r10 removed it -> polls doubled -> store visibility slowed -> +50% step time).
__global__ __attribute__((amdgpu_flat_work_group_size(256, 256), amdgpu_waves_per_eu(1, 1)))
void lstm_rec(
    const float* __restrict__ WhhF, const float* __restrict__ WhhB,
    const float* __restrict__ WihF, const float* __restrict__ WihB,
    const float* __restrict__ bihF, const float* __restrict__ bhhF,
    const float* __restrict__ bihB, const float* __restrict__ bhhB,
    const int* __restrict__ sent, const float* __restrict__ embed,
    const float* __restrict__ h0, const float* __restrict__ c0,
    unsigned* __restrict__ hfp, unsigned* __restrict__ hbp)
{
    const int bid = blockIdx.x;
    const int dir = bid >> 6;          // 0 fwd, 1 bwd
    const int b   = bid & 63;
    const float* __restrict__ Whh = dir ? WhhB : WhhF;
    const float* __restrict__ Wih = dir ? WihB : WihF;
    const float* __restrict__ bih = dir ? bihB : bihF;
    const float* __restrict__ bhh = dir ? bhhB : bhhF;
    unsigned* __restrict__ Hu = dir ? hbp : hfp;

    const int tid = threadIdx.x;
    const int r = tid >> 3;            // 0..31 local gate-row
    const int k = tid & 7;             // column chunk
    const int ul = r >> 2;             // 0..7 local unit
    const int g = r & 3;               // gate (i,f,g,o)
    const int unit = b * 8 + ul;
    const int row_g = g * HD + unit;   // global gate row in [0,2048)

    // 64 Whh + 64 Wih weights per thread as 32 NAMED float4s, pinned opaque (r3 mechanism)
    const float4* wp = (const float4*)(Whh + (size_t)row_g * HD + k * 64);
    const float4* up = (const float4*)(Wih + (size_t)row_g * E_DIM + k * 64);
#define WDECL(i) float4 w##i = wp[i]; float4 u##i = up[i];
    WDECL(0)  WDECL(1)  WDECL(2)  WDECL(3)
    WDECL(4)  WDECL(5)  WDECL(6)  WDECL(7)
    WDECL(8)  WDECL(9)  WDECL(10) WDECL(11)
    WDECL(12) WDECL(13) WDECL(14) WDECL(15)
#define WPIN(i) asm volatile("" : "+v"(w##i.x), "+v"(w##i.y), "+v"(w##i.z), "+v"(w##i.w), \
                                  "+v"(u##i.x), "+v"(u##i.y), "+v"(u##i.z), "+v"(u##i.w));
    WPIN(0)  WPIN(1)  WPIN(2)  WPIN(3)
    WPIN(4)  WPIN(5)  WPIN(6)  WPIN(7)
    WPIN(8)  WPIN(9)  WPIN(10) WPIN(11)
    WPIN(12) WPIN(13) WPIN(14) WPIN(15)

    __shared__ float hlds[2][8 * 68];  // double-buffered h row, stride 68 (conflict-free)
    __shared__ float elds[2][8 * 68];  // double-buffered emb row, same layout

    const int l  = tid & 63;
    const int l0 = l & 32;
    const bool cellln = (l & 31) == 0;
    float c = cellln ? c0[dir*HD + unit] : 0.f;

    // bias: constant across steps, added at k==0 lanes
    float xval = 0.f;
    if (k == 0) xval = bih[row_g] + bhh[row_g];

    const int ch  = tid >> 5;          // LDS staging slot
    const int off = (tid * 2) & 63;

    // ---- emb prologue: elds[0] <- row t(0); ereg <- row t(1) ----
    float2 ereg;
    {
        const int t0 = dir ? (S_LEN-1) : 0;
        const float2 ev = ((const float2*)(embed + (size_t)sent[t0] * E_DIM))[tid];
        elds[0][ch*68 + off]   = ev.x;
        elds[0][ch*68 + off+1] = ev.y;
        const int t1 = dir ? (S_LEN-2) : 1;
        ereg = ((const float2*)(embed + (size_t)sent[t1] * E_DIM))[tid];
    }

    for (int s = 0; s < S_LEN; ++s) {
        const int t_io = dir ? (S_LEN-1-s) : s;
        float* __restrict__ hl = hlds[s & 1];

        // write emb row for step s+1 into the other buffer (value prefetched last iter)
        {
            float* __restrict__ el = elds[(s+1) & 1];
            el[ch*68 + off]   = ereg.x;
            el[ch*68 + off+1] = ereg.y;
        }

        if (s == 0) {
            float2 hv = *(const float2*)(h0 + dir*HD + tid*2);
            hl[ch*68 + off]   = hv.x;
            hl[ch*68 + off+1] = hv.y;
        } else {
            const int prev = dir ? (t_io+1) : (t_io-1);
            const unsigned long long* src =
                (const unsigned long long*)(Hu + (size_t)prev*HD) + tid;
            unsigned long long v;
            do {
                v = __hip_atomic_load(src, __ATOMIC_RELAXED, __HIP_MEMORY_SCOPE_AGENT);
            } while ((unsigned)v == SENT || (unsigned)(v >> 32) == SENT);
            hl[ch*68 + off]   = __uint_as_float((unsigned)v);
            hl[ch*68 + off+1] = __uint_as_float((unsigned)(v >> 32));
        }
        __syncthreads();   // barrier 1 (staging complete)

        // prefetch emb row for step s+2 (consumed at next iteration's top)
        if (s + 2 < S_LEN) {
            const int t2 = dir ? (t_io - 2) : (t_io + 2);
            ereg = ((const float2*)(embed + (size_t)sent[t2] * E_DIM))[tid];
        }

        // 64-wide dot chunk over h (Whh) AND emb (Wih); LDS reads are 8-lane broadcasts
        float a0 = 0.f, a1 = 0.f, a2 = 0.f, a3 = 0.f;
        const float* __restrict__ hp = &hl[k * 68];
        const float* __restrict__ ep = &elds[s & 1][k * 68];
#define WDOT(i) { const float4 hv = *(const float4*)(hp + 4*(i)); \
        a0 += w##i.x*hv.x; a1 += w##i.y*hv.y; a2 += w##i.z*hv.z; a3 += w##i.w*hv.w; } \
        { const float4 ev4 = *(const float4*)(ep + 4*(i)); \
        a0 += u##i.x*ev4.x; a1 += u##i.y*ev4.y; a2 += u##i.z*ev4.z; a3 += u##i.w*ev4.w; }
        WDOT(0)  WDOT(1)  WDOT(2)  WDOT(3)
        WDOT(4)  WDOT(5)  WDOT(6)  WDOT(7)
        WDOT(8)  WDOT(9)  WDOT(10) WDOT(11)
        WDOT(12) WDOT(13) WDOT(14) WDOT(15)
        float acc = (a0 + a1) + (a2 + a3);

        // reduce across the 8 chunk lanes
        acc += __shfl_xor(acc, 1);
        acc += __shfl_xor(acc, 2);
        acc += __shfl_xor(acc, 4);
        const float pre = acc + xval;          // valid at k==0 lanes

        // activation: sigmoid for i,f,o; tanh (=2*sig(2x)-1) for g
        const float yy  = (g == 2) ? 2.f*pre : pre;
        const float sg  = 1.f / (1.f + __expf(-yy));
        const float act = (g == 2) ? 2.f*sg - 1.f : sg;

        const float a_i = __shfl(act, l0 + 0);
        const float a_f = __shfl(act, l0 + 8);
        const float a_g = __shfl(act, l0 + 16);
        const float a_o = __shfl(act, l0 + 24);

        float hval = 0.f;
        if (cellln) {
            c = a_f*c + a_i*a_g;
            const float th = 2.f / (1.f + __expf(-2.f*c)) - 1.f;
            hval = a_o * th;
        }
        // pair the two units of this wave into one 8B agent-scope store (lane 0 of wave)
        const float h_hi = __shfl(hval, l0 ? 96 : 32, 64);
        if (l == 0) {
            const unsigned long long pv =
                (unsigned long long)__float_as_uint(hval) |
                ((unsigned long long)__float_as_uint(h_hi) << 32);
            unsigned long long* dst =
                (unsigned long long*)(Hu + (size_t)t_io*HD) + (unit >> 1);
            __hip_atomic_store(dst, pv, __ATOMIC_RELAXED, __HIP_MEMORY_SCOPE_AGENT);
        }
        __syncthreads();   // barrier 2 (poll-pressure throttle + LDS protection)
    }
}

// ---------------- feats: [hf,hb] @ Wout.T + bout ----------------
__global__ __launch_bounds__(256) void feats_k(
    const float* __restrict__ hf, const float* __restrict__ hb,
    const float* __restrict__ Wout, const float* __restrict__ bout,
    float* __restrict__ feats)
{
    int idx = blockIdx.x * blockDim.x + threadIdx.x;
    if (idx >= S_LEN * NTAG) return;
    int t = idx / NTAG, tag = idx - t*NTAG;
    const float* __restrict__ wf  = Wout + (size_t)tag * (2*HD);
    const float* __restrict__ ha  = hf + (size_t)t * HD;
    const float* __restrict__ hbr = hb + (size_t)t * HD;
    float a0=0.f, a1=0.f, a2=0.f, a3=0.f;
    for (int i = 0; i < HD; i += 4) {
        float4 h4 = *(const float4*)(ha + i);
        float4 w4 = *(const float4*)(wf + i);
        a0 += h4.x*w4.x; a1 += h4.y*w4.y; a2 += h4.z*w4.z; a3 += h4.w*w4.w;
    }
    for (int i = 0; i < HD; i += 4) {
        float4 h4 = *(const float4*)(hbr + i);
        float4 w4 = *(const float4*)(wf + HD + i);
        a0 += h4.x*w4.x; a1 += h4.y*w4.y; a2 += h4.z*w4.z; a3 += h4.w*w4.w;
    }
    feats[idx] = a0+a1+a2+a3 + bout[tag];
}

// ---------------- Viterbi pass A: per-chunk max-plus matrix composition ----------------
__global__ __launch_bounds__(64) void vit_chunk(
    const float* __restrict__ feats, const float* __restrict__ trans,
    float* __restrict__ Cws)          // [NCHUNK][12][12]
{
    const int chunk = blockIdx.x;
    const int j = threadIdx.x;
    __shared__ float tr[NTAG*NTAG];
    for (int i = threadIdx.x; i < NTAG*NTAG; i += 64) tr[i] = trans[i];
    __syncthreads();
    if (j >= NTAG) return;

    const int t0 = chunk * CLEN;
    float c[NTAG];
    {
        const float* f0 = feats + (size_t)t0 * NTAG;
        #pragma unroll
        for (int i = 0; i < NTAG; ++i) c[i] = tr[i*NTAG + j] + f0[i];
    }
    for (int t = 1; t < CLEN; ++t) {
        const float* ft = feats + (size_t)(t0 + t) * NTAG;
        float cn[NTAG];
        #pragma unroll
        for (int i = 0; i < NTAG; ++i) {
            float m = tr[i*NTAG + 0] + c[0];
            #pragma unroll
            for (int k = 1; k < NTAG; ++k) m = fmaxf(m, tr[i*NTAG + k] + c[k]);
            cn[i] = m + ft[i];
        }
        #pragma unroll
        for (int i = 0; i < NTAG; ++i) c[i] = cn[i];
    }
    #pragma unroll
    for (int i = 0; i < NTAG; ++i) Cws[(size_t)chunk*NTAG*NTAG + i*NTAG + j] = c[i];
}

// ---------------- Viterbi pass B: serial scan over 256 chunk matrices ----------------
__global__ __launch_bounds__(64) void vit_scan(
    const float* __restrict__ Cws, float* __restrict__ fvs)   // fvs: [NCHUNK+1][16]
{
    const int i = threadIdx.x;
    float fv[NTAG];
    #pragma unroll
    for (int p = 0; p < NTAG; ++p) fv[p] = (p == TAG_START) ? 0.f : NEGV;

    for (int c = 0; c < NCHUNK; ++c) {
        if (i < NTAG) fvs[c*16 + i] = fv[i];
        float m = -3.4e38f;
        if (i < NTAG) {
            const float* row = Cws + (size_t)c*NTAG*NTAG + i*NTAG;
            #pragma unroll
            for (int j = 0; j < NTAG; ++j) m = fmaxf(m, row[j] + fv[j]);
        }
        #pragma unroll
        for (int p = 0; p < NTAG; ++p) fv[p] = __shfl(m, p);
    }
    if (i < NTAG) fvs[NCHUNK*16 + i] = fv[i];
}

// ---------------- Viterbi pass C: parallel backpointer replay (reference semantics) ----------------
__global__ __launch_bounds__(64) void vit_bp(
    const float* __restrict__ feats, const float* __restrict__ trans,
    const float* __restrict__ fvs, unsigned char* __restrict__ bp)   // bp: [S_LEN][16]
{
    const int chunk = blockIdx.x;
    const int ln = threadIdx.x;
    float tr[NTAG];
    float fv = 0.f;
    if (ln < NTAG) {
        #pragma unroll
        for (int p = 0; p < NTAG; ++p) tr[p] = trans[ln*NTAG + p];
        fv = fvs[chunk*16 + ln];
    }
    const int t0 = chunk * CLEN;
    for (int t = 0; t < CLEN; ++t) {
        float sc[NTAG];
        #pragma unroll
        for (int p = 0; p < NTAG; ++p) sc[p] = __shfl(fv, p) + tr[p];
        float best = sc[0]; int arg = 0;
        #pragma unroll
        for (int p = 1; p < NTAG; ++p)
            if (sc[p] > best) { best = sc[p]; arg = p; }   // strict > = first-max (np argmax)
        if (ln < NTAG) {
            bp[(size_t)(t0 + t)*16 + ln] = (unsigned char)arg;
            fv = best + feats[(size_t)(t0 + t)*NTAG + ln];
        }
    }
}

// ---------------- Viterbi pass D: terminal + backtrace ----------------
__global__ __launch_bounds__(256) void vit_bt(
    const unsigned char* __restrict__ bp, const float* __restrict__ fvs,
    const float* __restrict__ trans, float* __restrict__ out)
{
    __shared__ unsigned char bpl[S_LEN * 16];   // 32 KB
    {
        const float4* src = (const float4*)bp;
        float4* dst = (float4*)bpl;
        for (int i = threadIdx.x; i < S_LEN*16/16; i += 256) dst[i] = src[i];
    }
    __syncthreads();
    if (threadIdx.x == 0) {
        float best = -3.4e38f; int arg = 0;
        #pragma unroll
        for (int i = 0; i < NTAG; ++i) {
            const float v = fvs[NCHUNK*16 + i] + trans[TAG_STOP*NTAG + i];
            if (v > best) { best = v; arg = i; }
        }
        out[0] = best;
        int tag = arg;
        for (int t = S_LEN-1; t >= 0; --t) {
            out[1+t] = (float)tag;
            tag = bpl[t*16 + tag];
        }
    }
}

// ---------------- launch ----------------
extern "C" void kernel_launch(void* const* d_in, const int* in_sizes, int n_in,
                              void* d_out, int out_size, void* d_ws, size_t ws_size,
                              hipStream_t stream)
{
    const int*   sent  = (const int*)d_in[0];
    const float* embed = (const float*)d_in[1];
    const float* WihF  = (const float*)d_in[2];
    const float* WhhF  = (const float*)d_in[3];
    const float* bihF  = (const float*)d_in[4];
    const float* bhhF  = (const float*)d_in[5];
    const float* WihB  = (const float*)d_in[6];
    const float* WhhB  = (const float*)d_in[7];
    const float* bihB  = (const float*)d_in[8];
    const float* bhhB  = (const float*)d_in[9];
    const float* h0    = (const float*)d_in[10];
    const float* c0    = (const float*)d_in[11];
    const float* Wout  = (const float*)d_in[12];
    const float* bout  = (const float*)d_in[13];
    const float* trans = (const float*)d_in[14];
    float* out = (float*)d_out;

    float* ws = (float*)d_ws;
    float* hf    = ws;                                       // 4 MB
    float* hb    = hf + (size_t)S_LEN * HD;                  // 4 MB
    float* feats = hb + (size_t)S_LEN * HD;                  // 96 KB
    float* Cws   = feats + (size_t)S_LEN * NTAG;             // 576 KB
    float* fvs   = Cws + (size_t)NCHUNK * NTAG * NTAG;       // 16.4 KB
    unsigned char* bp = (unsigned char*)(fvs + (size_t)(NCHUNK+1) * 16);  // 32 KB

    // 1) sentinel-fill both h buffers (byte pattern 0x7F -> fp32 3.39e38)
    hipMemsetAsync(hf, 0x7F, (size_t)2 * S_LEN * HD * sizeof(float), stream);
    // 2) recurrence with fused X computation, both directions concurrently
    lstm_rec<<<128, 256, 0, stream>>>(WhhF, WhhB, WihF, WihB,
                                      bihF, bhhF, bihB, bhhB,
                                      sent, embed, h0, c0,
                                      (unsigned*)hf, (unsigned*)hb);
    // 3) emission features
    {
        int n = S_LEN * NTAG;
        feats_k<<<(n + 255)/256, 256, 0, stream>>>(hf, hb, Wout, bout, feats);
    }
    // 4) Viterbi: parallel tropical scan (A,B,C) + backtrace (D)
    vit_chunk<<<NCHUNK, 64, 0, stream>>>(feats, trans, Cws);
    vit_scan<<<1, 64, 0, stream>>>(Cws, fvs);
    vit_bp<<<NCHUNK, 64, 0, stream>>>(feats, trans, fvs, bp);
    vit_bt<<<1, 256, 0, stream>>>(bp, fvs, trans, out);
}